// Round 4
// baseline (196.140 us; speedup 1.0000x reference)
//
#include <hip/hip_runtime.h>

// B=4, H=8, Nt=Nc=2048, D=512, E=64, scale = 1/64 folded into Wq at cast.
#define B_   4
#define H_   8
#define NSEQ 2048
#define D_   512
#define E_   64

typedef __bf16 bf16x8 __attribute__((ext_vector_type(8)));
typedef float  f32x4  __attribute__((ext_vector_type(4)));

__device__ __forceinline__ unsigned short f2b(float f) {
    __bf16 h = (__bf16)f;                     // RNE
    return __builtin_bit_cast(unsigned short, h);
}
__device__ __forceinline__ bf16x8 ld_frag(const unsigned short* p) {
    return *reinterpret_cast<const bf16x8*>(p);
}
// wave-private LDS write->read ordering
__device__ __forceinline__ void wave_lds_fence() {
    __asm__ __volatile__("s_waitcnt lgkmcnt(0)" ::: "memory");
}
// async global->LDS, 16B per lane: LDS dest = wave-uniform base + lane*16.
__device__ __forceinline__ void async_copy16(const void* g, const unsigned short* l) {
    __builtin_amdgcn_global_load_lds(
        (const __attribute__((address_space(1))) unsigned int*)g,
        (__attribute__((address_space(3))) unsigned int*)l, 16, 0, 0);
}

// ---------------------------------------------------------------------------
// Cast + transpose W: [H][D][E] fp32 -> [he][d] bf16 (y=0..2); Wout (y=3).
// Wq (y=2) pre-scaled by 1/64 (exact exponent shift).
// ---------------------------------------------------------------------------
__global__ __launch_bounds__(256)
void cast_w_kernel(const float* __restrict__ Wk, const float* __restrict__ Wv,
                   const float* __restrict__ Wq, const float* __restrict__ Wo,
                   unsigned short* __restrict__ okt, unsigned short* __restrict__ ovt,
                   unsigned short* __restrict__ oqt, unsigned short* __restrict__ oo) {
    int idx = blockIdx.x * 256 + threadIdx.x;   // < 262144
    int y = blockIdx.y;
    if (y == 3) { oo[idx] = f2b(Wo[idx]); return; }
    const float* src = y == 0 ? Wk : (y == 1 ? Wv : Wq);
    unsigned short* dst = y == 0 ? okt : (y == 1 ? ovt : oqt);
    float scl = (y == 2) ? 0.015625f : 1.0f;
    int hh = idx >> 15, rem = idx & 32767, d = rem >> 6, e = rem & 63;
    dst[hh * 32768 + e * 512 + d] = f2b(src[idx] * scl);   // [(h*64+e)][d]
}

// ---------------------------------------------------------------------------
// X cast: fp32 [8192][512] -> bf16 [8192][512], y selects q/k/v. Pure
// memory-bound (48 MB rd + 24 MB wr ~= 12 us at HBM ceiling). float4 loads.
// ---------------------------------------------------------------------------
__global__ __launch_bounds__(256)
void xcast_kernel(const float* __restrict__ q, const float* __restrict__ k,
                  const float* __restrict__ v,
                  unsigned short* __restrict__ qx, unsigned short* __restrict__ kx,
                  unsigned short* __restrict__ vx) {
    const int y = blockIdx.y;
    const float* src = y == 0 ? q : (y == 1 ? k : v);
    unsigned short* dst = y == 0 ? qx : (y == 1 ? kx : vx);
    #pragma unroll
    for (int i = 0; i < 4; ++i) {
        int e = blockIdx.x * 4096 + i * 1024 + threadIdx.x * 4;
        float4 f = *reinterpret_cast<const float4*>(src + e);
        *reinterpret_cast<ushort4*>(dst + e) =
            make_ushort4(f2b(f.x), f2b(f.y), f2b(f.z), f2b(f.w));
    }
}

// ---------------------------------------------------------------------------
// Projection NT-GEMM (pure bf16): C[m][he] = sum_d X[m][d]*Wt[he][d].
// 8192x512x512, which: 0=Q 1=K 2=V. 128x64 tile, BK=64. (unchanged)
// ---------------------------------------------------------------------------
__global__ __launch_bounds__(256, 3)
void proj_gemm(const unsigned short* __restrict__ qx,
               const unsigned short* __restrict__ kx,
               const unsigned short* __restrict__ vx,
               const unsigned short* __restrict__ wqt,
               const unsigned short* __restrict__ wkt,
               const unsigned short* __restrict__ wvt,
               unsigned short* __restrict__ qb, unsigned short* __restrict__ kb,
               unsigned short* __restrict__ vtb) {
    const int m0  = blockIdx.x * 128;
    const int no0 = blockIdx.y * 64;
    const int which = blockIdx.z;
    const int tid = threadIdx.x;
    const int wave = tid >> 6, lane = tid & 63;
    const int quad = lane >> 4, l16 = lane & 15;

    const unsigned short* X = which == 0 ? qx : (which == 1 ? kx : vx);
    const unsigned short* W = which == 0 ? wqt : (which == 1 ? wkt : wvt);

    __shared__ unsigned short Ab[2][8192];   // 2 x 16 KB (128 rows x 128 B)
    __shared__ unsigned short Bb[2][4096];   // 2 x  8 KB ( 64 rows x 128 B)

    const unsigned short* Xp = X + (size_t)m0 * D_;
    const unsigned short* Wp = W + (size_t)no0 * D_;

    const int swzF = (l16 & 7) << 4;          // frag-read byte XOR (row≡l16 mod 8)
    const int r8   = lane >> 3;               // stage: row within 8-row slab
    const int sg   = lane & 7;                // stage: 16B slot in 128B row
    const int colK = (sg * 16) ^ ((r8 & 7) << 4);  // pre-swizzled source byte col

    #define PROJ_STAGE(kt, buf)                                                \
        {   _Pragma("unroll")                                                  \
            for (int i = 0; i < 4; ++i)                                        \
                async_copy16(                                                  \
                    (const char*)(Xp + (size_t)(wave * 32 + i * 8 + r8) * D_ + \
                                  (kt) * 64) + colK,                           \
                    &Ab[buf][(wave * 32 + i * 8) * 64]);                       \
            _Pragma("unroll")                                                  \
            for (int i = 0; i < 2; ++i)                                        \
                async_copy16(                                                  \
                    (const char*)(Wp + (size_t)(wave * 16 + i * 8 + r8) * D_ + \
                                  (kt) * 64) + colK,                           \
                    &Bb[buf][(wave * 16 + i * 8) * 64]);                       \
        }

    PROJ_STAGE(0, 0)
    __syncthreads();                          // vmcnt drain: tile 0 resident

    const f32x4 z = {0.f, 0.f, 0.f, 0.f};
    f32x4 acc[2][4];
    #pragma unroll
    for (int i = 0; i < 2; ++i)
        #pragma unroll
        for (int j = 0; j < 4; ++j) acc[i][j] = z;

    for (int kt = 0; kt < 8; ++kt) {
        const int cur = kt & 1;
        if (kt + 1 < 8) PROJ_STAGE(kt + 1, 1 - cur)   // in flight over compute
        #pragma unroll
        for (int kk = 0; kk < 2; ++kk) {
            const int co = ((kk * 64 + quad * 16) ^ swzF) >> 1;
            bf16x8 bfr[4];
            #pragma unroll
            for (int nt = 0; nt < 4; ++nt)
                bfr[nt] = ld_frag(&Bb[cur][(nt * 16 + l16) * 64 + co]);
            #pragma unroll
            for (int mt = 0; mt < 2; ++mt) {
                bf16x8 af = ld_frag(&Ab[cur][(wave * 32 + mt * 16 + l16) * 64 + co]);
                #pragma unroll
                for (int nt = 0; nt < 4; ++nt)
                    acc[mt][nt] = __builtin_amdgcn_mfma_f32_16x16x32_bf16(
                        af, bfr[nt], acc[mt][nt], 0, 0, 0);
            }
        }
        __syncthreads();                      // drains vmcnt (tile kt+1) + lgkm
    }

    // epilogue: overlay staging on Ab (32 KB contiguous)
    if (which != 2) {
        unsigned short (*Os)[72] = reinterpret_cast<unsigned short(*)[72]>(&Ab[0][0]);
        #pragma unroll
        for (int mt = 0; mt < 2; ++mt)
            #pragma unroll
            for (int nt = 0; nt < 4; ++nt)
                #pragma unroll
                for (int r = 0; r < 4; ++r)
                    Os[wave * 32 + mt * 16 + quad * 4 + r][nt * 16 + l16] =
                        f2b(acc[mt][nt][r]);
        __syncthreads();
        unsigned short* Y = (which == 0 ? qb : kb);
        #pragma unroll
        for (int i = 0; i < 4; ++i) {           // 128 rows x 8 uint4
            int idx = tid + i * 256;
            int row = idx >> 3, seg = idx & 7;
            *reinterpret_cast<uint4*>(Y + (size_t)(m0 + row) * D_ + no0 + seg * 8) =
                *reinterpret_cast<const uint4*>(&Os[row][seg * 8]);
        }
    } else {
        unsigned short (*Ot)[136] = reinterpret_cast<unsigned short(*)[136]>(&Ab[0][0]);
        #pragma unroll
        for (int mt = 0; mt < 2; ++mt)
            #pragma unroll
            for (int nt = 0; nt < 4; ++nt) {
                ushort4 o = make_ushort4(f2b(acc[mt][nt][0]), f2b(acc[mt][nt][1]),
                                         f2b(acc[mt][nt][2]), f2b(acc[mt][nt][3]));
                *reinterpret_cast<ushort4*>(
                    &Ot[nt * 16 + l16][wave * 32 + mt * 16 + quad * 4]) = o;
            }
        __syncthreads();
        const int b = m0 >> 11, nloc = m0 & 2047;
        #pragma unroll
        for (int i = 0; i < 4; ++i) {           // 64 he-rows x 16 uint4
            int idx = tid + i * 256;
            int lhe = idx >> 4, seg = idx & 15;
            int ghe = no0 + lhe;                 // h = ghe>>6, e = ghe&63
            *reinterpret_cast<uint4*>(
                vtb + ((size_t)(b * H_ + (ghe >> 6)) * E_ + (ghe & 63)) * NSEQ +
                nloc + seg * 8) =
                *reinterpret_cast<const uint4*>(&Ot[lhe][seg * 8]);
        }
    }
    #undef PROJ_STAGE
}

// ---------------------------------------------------------------------------
// Flash attention, transposed-S. 64-row Q tiles (grid 1024), 128-thread
// blocks, 2 waves x 32 Q-rows each (was 4 x 16).
//   St = K·Q^T ; P = exp(St) via wave-private LDS ; O^T = V^T·P^T.
//
// Round-3 PMC showed the DS pipe ~80% busy (K/V tiles re-read per wave,
// amortized over only 16 q-rows). 32 q-rows/wave feeds each K/V fragment
// read into TWO MFMAs -> per-q-row LDS cost 15 -> 9 cyc. LDS layout, XOR
// swizzle, global_load_lds staging, and the one-barrier pipeline are
// unchanged; only row ownership generalizes (wave owns rows [32w,32w+32)
// of K/V staging and of P; P reads stay wave-private).
// LDS 40960 B -> 4 blocks/CU exact, grid 1024 = 256 CU x 4, no tail.
// ---------------------------------------------------------------------------
__global__ __launch_bounds__(128, 2)
void attn_kernel(const unsigned short* __restrict__ qbp,
                 const unsigned short* __restrict__ kbp,
                 const unsigned short* __restrict__ vtbp,
                 unsigned short* __restrict__ aob) {
    const int L = blockIdx.x;
    const int bh = L & 31, qt = L >> 5;      // L%8 pattern -> XCD K/V affinity
    const int b = bh >> 3, h = bh & 7;
    const int n0 = qt * 64;
    const int tid = threadIdx.x;             // 0..127
    const int wave = tid >> 6, lane = tid & 63;   // 2 waves
    const int quad = lane >> 4, l16 = lane & 15;

    __shared__ unsigned short Ks[2][4096];   // 16 KiB (dbuf K, 64x64, 128-B rows)
    __shared__ unsigned short Vs[2][4096];   // 16 KiB (dbuf V^T)
    __shared__ unsigned short Ps[4096];      //  8 KiB (64 q-rows x 64 keys)

    const unsigned short* kbase = kbp + (size_t)(b * NSEQ) * D_ + h * 64;
    const unsigned short* vbase = vtbp + (size_t)(b * H_ + h) * E_ * NSEQ;

    const int swzF = (l16 & 7) << 4;   // byte XOR for frag/P rows (row ≡ l16 mod 8)
    const int r8   = lane >> 3;        // staging: lane covers row r8 of an 8-row slab
    const int sg   = lane & 7;         //          16B slot within the 128B row
    const int colK = (sg * 16) ^ ((r8 & 7) << 4);  // pre-swizzled source column

    // Q B-frags, loaded once. Wave owns q-rows n0 + wave*32 .. +32 (2 groups).
    bf16x8 qf[2][2];
    #pragma unroll
    for (int qg = 0; qg < 2; ++qg)
        #pragma unroll
        for (int kk = 0; kk < 2; ++kk)
            qf[qg][kk] = ld_frag(
                qbp + (size_t)(b * NSEQ + n0 + wave * 32 + qg * 16 + l16) * D_ +
                h * 64 + kk * 32 + quad * 8);

    // wave stages rows [32w, 32w+32) of both K and V^T tiles (4 slabs each)
    #define ATTN_STAGE(j, buf)                                                 \
        {   _Pragma("unroll")                                                  \
            for (int i = 0; i < 4; ++i) {                                      \
                async_copy16(                                                  \
                    (const char*)(kbase +                                      \
                        (size_t)((j) * 64 + wave * 32 + i * 8 + r8) * D_) + colK, \
                    &Ks[buf][(wave * 32 + i * 8) * 64]);                       \
                async_copy16(                                                  \
                    (const char*)(vbase +                                      \
                        (size_t)(wave * 32 + i * 8 + r8) * NSEQ + (j) * 64) + colK, \
                    &Vs[buf][(wave * 32 + i * 8) * 64]);                       \
            } }

    ATTN_STAGE(0, 0)
    __syncthreads();                            // vmcnt drain: tile 0 resident

    const f32x4 z = {0.f, 0.f, 0.f, 0.f};
    f32x4 oacc[2][4];
    #pragma unroll
    for (int qg = 0; qg < 2; ++qg)
        #pragma unroll
        for (int eg = 0; eg < 4; ++eg) oacc[qg][eg] = z;
    float lacc[2] = {0.f, 0.f};

    for (int j = 0; j < NSEQ / 64; ++j) {
        const int cur = j & 1;
        if (j + 1 < NSEQ / 64) ATTN_STAGE(j + 1, 1 - cur)   // in flight over compute

        // St = K·Q^T : C[key = mg*16+quad*4+r][qrow = l16 in group qg]
        // ONE K-frag read feeds BOTH q-groups (the amortization).
        f32x4 sacc[2][4];
        #pragma unroll
        for (int qg = 0; qg < 2; ++qg)
            #pragma unroll
            for (int mg = 0; mg < 4; ++mg) sacc[qg][mg] = z;
        #pragma unroll
        for (int kk = 0; kk < 2; ++kk) {
            const int co = ((kk * 64 + quad * 16) ^ swzF) >> 1;
            #pragma unroll
            for (int mg = 0; mg < 4; ++mg) {
                bf16x8 af = ld_frag(&Ks[cur][(mg * 16 + l16) * 64 + co]);
                sacc[0][mg] = __builtin_amdgcn_mfma_f32_16x16x32_bf16(
                    af, qf[0][kk], sacc[0][mg], 0, 0, 0);
                sacc[1][mg] = __builtin_amdgcn_mfma_f32_16x16x32_bf16(
                    af, qf[1][kk], sacc[1][mg], 0, 0, 0);
            }
        }

        // exp (m=0), commit P (4 consecutive keys per write), defer l
        #pragma unroll
        for (int qg = 0; qg < 2; ++qg) {
            float ls = 0.f;
            const int prow = (wave * 32 + qg * 16 + l16) * 64;
            #pragma unroll
            for (int mg = 0; mg < 4; ++mg) {
                float p0 = __expf(sacc[qg][mg][0]);
                float p1 = __expf(sacc[qg][mg][1]);
                float p2 = __expf(sacc[qg][mg][2]);
                float p3 = __expf(sacc[qg][mg][3]);
                ls += (p0 + p1) + (p2 + p3);
                ushort4 pk = make_ushort4(f2b(p0), f2b(p1), f2b(p2), f2b(p3));
                *reinterpret_cast<ushort4*>(
                    &Ps[prow + ((((mg * 32 + quad * 8) ^ swzF)) >> 1)]) = pk;
            }
            lacc[qg] += ls;
        }
        wave_lds_fence();

        // O^T += V^T·P^T  (P rows are wave-private; one V-frag feeds both qg)
        #pragma unroll
        for (int kkv = 0; kkv < 2; ++kkv) {
            const int co = ((kkv * 64 + quad * 16) ^ swzF) >> 1;
            bf16x8 pf0 = ld_frag(&Ps[(wave * 32 + l16) * 64 + co]);
            bf16x8 pf1 = ld_frag(&Ps[(wave * 32 + 16 + l16) * 64 + co]);
            #pragma unroll
            for (int eg = 0; eg < 4; ++eg) {
                bf16x8 af = ld_frag(&Vs[cur][(eg * 16 + l16) * 64 + co]);
                oacc[0][eg] = __builtin_amdgcn_mfma_f32_16x16x32_bf16(
                    af, pf0, oacc[0][eg], 0, 0, 0);
                oacc[1][eg] = __builtin_amdgcn_mfma_f32_16x16x32_bf16(
                    af, pf1, oacc[1][eg], 0, 0, 0);
            }
        }

        __syncthreads();   // drains vmcnt (tile j+1 committed) + lgkm; flips buffers
    }

    // l-reduction across quads (each quad holds a different key subset)
    #pragma unroll
    for (int qg = 0; qg < 2; ++qg) {
        float s = lacc[qg];
        s += __shfl_xor(s, 16);
        s += __shfl_xor(s, 32);
        float li = 1.0f / s;
        unsigned short* op =
            aob + (size_t)(b * NSEQ + n0 + wave * 32 + qg * 16 + l16) * D_ +
            h * 64 + quad * 4;
        #pragma unroll
        for (int eg = 0; eg < 4; ++eg) {
            ushort4 o = make_ushort4(f2b(oacc[qg][eg][0] * li),
                                     f2b(oacc[qg][eg][1] * li),
                                     f2b(oacc[qg][eg][2] * li),
                                     f2b(oacc[qg][eg][3] * li));
            *reinterpret_cast<ushort4*>(op + eg * 16) = o;
        }
    }
    #undef ATTN_STAGE
}

// ---------------------------------------------------------------------------
// Output NT-GEMM: Out[m][o] = sum_d aob[m][d] * Wout[o][d]. 8192x512x512.
// Same global_load_lds structure as proj_gemm; fp32 direct-store epilogue.
// ---------------------------------------------------------------------------
__global__ __launch_bounds__(256, 3)
void out_gemm(const unsigned short* __restrict__ A,
              const unsigned short* __restrict__ Wo,
              float* __restrict__ Out) {
    const int m0  = blockIdx.x * 128;
    const int no0 = blockIdx.y * 64;
    const int tid = threadIdx.x;
    const int wave = tid >> 6, lane = tid & 63;
    const int quad = lane >> 4, l16 = lane & 15;

    __shared__ unsigned short Ab[2][8192];
    __shared__ unsigned short Bb[2][4096];

    const unsigned short* Ap = A + (size_t)m0 * D_;
    const unsigned short* Bp = Wo + (size_t)no0 * D_;

    const int swzF = (l16 & 7) << 4;
    const int r8   = lane >> 3;
    const int sg   = lane & 7;
    const int colK = (sg * 16) ^ ((r8 & 7) << 4);

    #define OUT_STAGE(kt, buf)                                                 \
        {   _Pragma("unroll")                                                  \
            for (int i = 0; i < 4; ++i)                                        \
                async_copy16(                                                  \
                    (const char*)(Ap + (size_t)(wave * 32 + i * 8 + r8) * D_ + \
                                  (kt) * 64) + colK,                           \
                    &Ab[buf][(wave * 32 + i * 8) * 64]);                       \
            _Pragma("unroll")                                                  \
            for (int i = 0; i < 2; ++i)                                        \
                async_copy16(                                                  \
                    (const char*)(Bp + (size_t)(wave * 16 + i * 8 + r8) * D_ + \
                                  (kt) * 64) + colK,                           \
                    &Bb[buf][(wave * 16 + i * 8) * 64]);                       \
        }

    OUT_STAGE(0, 0)
    __syncthreads();

    const f32x4 z = {0.f, 0.f, 0.f, 0.f};
    f32x4 acc[2][4];
    #pragma unroll
    for (int i = 0; i < 2; ++i)
        #pragma unroll
        for (int j = 0; j < 4; ++j) acc[i][j] = z;

    for (int kt = 0; kt < 8; ++kt) {
        const int cur = kt & 1;
        if (kt + 1 < 8) OUT_STAGE(kt + 1, 1 - cur)
        #pragma unroll
        for (int kk = 0; kk < 2; ++kk) {
            const int co = ((kk * 64 + quad * 16) ^ swzF) >> 1;
            bf16x8 bfr[4];
            #pragma unroll
            for (int nt = 0; nt < 4; ++nt)
                bfr[nt] = ld_frag(&Bb[cur][(nt * 16 + l16) * 64 + co]);
            #pragma unroll
            for (int mt = 0; mt < 2; ++mt) {
                bf16x8 af = ld_frag(&Ab[cur][(wave * 32 + mt * 16 + l16) * 64 + co]);
                #pragma unroll
                for (int nt = 0; nt < 4; ++nt)
                    acc[mt][nt] = __builtin_amdgcn_mfma_f32_16x16x32_bf16(
                        af, bfr[nt], acc[mt][nt], 0, 0, 0);
            }
        }
        __syncthreads();
    }
    #pragma unroll
    for (int mt = 0; mt < 2; ++mt)
        #pragma unroll
        for (int nt = 0; nt < 4; ++nt)
            #pragma unroll
            for (int r = 0; r < 4; ++r)
                Out[(size_t)(m0 + wave * 32 + mt * 16 + quad * 4 + r) * D_ +
                    no0 + nt * 16 + l16] = acc[mt][nt][r];
    #undef OUT_STAGE
}

// ---------------------------------------------------------------------------
extern "C" void kernel_launch(void* const* d_in, const int* in_sizes, int n_in,
                              void* d_out, int out_size, void* d_ws, size_t ws_size,
                              hipStream_t stream) {
    const float* keys   = (const float*)d_in[0];
    const float* values = (const float*)d_in[1];
    const float* query  = (const float*)d_in[2];
    const float* Wk     = (const float*)d_in[3];
    const float* Wv     = (const float*)d_in[4];
    const float* Wq     = (const float*)d_in[5];
    const float* Wout   = (const float*)d_in[6];
    float* out = (float*)d_out;

    unsigned short* ws16 = (unsigned short*)d_ws;
    const size_t XN = (size_t)B_ * NSEQ * D_;      // 4,194,304
    const size_t WN = (size_t)H_ * D_ * E_;        // 262,144
    unsigned short* wkt = ws16;                    // [he][d]
    unsigned short* wvt = wkt + WN;
    unsigned short* wqt = wvt + WN;                // pre-scaled by 1/64
    unsigned short* wob = wqt + WN;
    unsigned short* qb  = wob + WN;                // [8192][512], col=h*64+e
    unsigned short* kb  = qb + XN;                 // [8192][512]
    unsigned short* vtb = kb + XN;                 // [b][h][e][n]
    unsigned short* aob = vtb + XN;                // [8192][512] head-concat
    unsigned short* qx  = aob + XN;                // bf16 query  [8192][512]
    unsigned short* kx  = qx + XN;                 // bf16 keys   [8192][512]
    unsigned short* vx  = aob;                     // bf16 values ALIASES aob:
                                                   // vx dead after proj; aob
                                                   // written only by attn (later)

    cast_w_kernel<<<dim3(1024, 4), 256, 0, stream>>>(Wk, Wv, Wq, Wout,
                                                     wkt, wvt, wqt, wob);

    xcast_kernel<<<dim3(1024, 3), 256, 0, stream>>>(query, keys, values,
                                                    qx, kx, vx);

    proj_gemm<<<dim3(64, 8, 3), 256, 0, stream>>>(
        qx, kx, vx, wqt, wkt, wvt, qb, kb, vtb);

    attn_kernel<<<dim3(1024), 128, 0, stream>>>(qb, kb, vtb, aob);

    out_gemm<<<dim3(64, 8), 256, 0, stream>>>(aob, wob, out);
}

// Round 5
// 187.200 us; speedup vs baseline: 1.0478x; 1.0478x over previous
//
#include <hip/hip_runtime.h>

// B=4, H=8, Nt=Nc=2048, D=512, E=64, scale = 1/64 folded into Wq at cast.
#define B_   4
#define H_   8
#define NSEQ 2048
#define D_   512
#define E_   64

typedef __bf16 bf16x8 __attribute__((ext_vector_type(8)));
typedef float  f32x4  __attribute__((ext_vector_type(4)));
typedef float  f32x16 __attribute__((ext_vector_type(16)));

__device__ __forceinline__ unsigned short f2b(float f) {
    __bf16 h = (__bf16)f;                     // RNE
    return __builtin_bit_cast(unsigned short, h);
}
__device__ __forceinline__ unsigned pk2(float a, float b) {
    return (unsigned)f2b(a) | ((unsigned)f2b(b) << 16);
}
__device__ __forceinline__ bf16x8 ld_frag(const unsigned short* p) {
    return *reinterpret_cast<const bf16x8*>(p);
}
// async global->LDS, 16B per lane: LDS dest = wave-uniform base + lane*16.
__device__ __forceinline__ void async_copy16(const void* g, const unsigned short* l) {
    __builtin_amdgcn_global_load_lds(
        (const __attribute__((address_space(1))) unsigned int*)g,
        (__attribute__((address_space(3))) unsigned int*)l, 16, 0, 0);
}

// ---------------------------------------------------------------------------
// Cast + transpose W: [H][D][E] fp32 -> [he][d] bf16 (y=0..2); Wout (y=3).
// Wq (y=2) pre-scaled by 1/64 (exact exponent shift).
// ---------------------------------------------------------------------------
__global__ __launch_bounds__(256)
void cast_w_kernel(const float* __restrict__ Wk, const float* __restrict__ Wv,
                   const float* __restrict__ Wq, const float* __restrict__ Wo,
                   unsigned short* __restrict__ okt, unsigned short* __restrict__ ovt,
                   unsigned short* __restrict__ oqt, unsigned short* __restrict__ oo) {
    int idx = blockIdx.x * 256 + threadIdx.x;   // < 262144
    int y = blockIdx.y;
    if (y == 3) { oo[idx] = f2b(Wo[idx]); return; }
    const float* src = y == 0 ? Wk : (y == 1 ? Wv : Wq);
    unsigned short* dst = y == 0 ? okt : (y == 1 ? ovt : oqt);
    float scl = (y == 2) ? 0.015625f : 1.0f;
    int hh = idx >> 15, rem = idx & 32767, d = rem >> 6, e = rem & 63;
    dst[hh * 32768 + e * 512 + d] = f2b(src[idx] * scl);   // [(h*64+e)][d]
}

// ---------------------------------------------------------------------------
// X cast: fp32 [8192][512] -> bf16 [8192][512], y selects q/k/v.
// ---------------------------------------------------------------------------
__global__ __launch_bounds__(256)
void xcast_kernel(const float* __restrict__ q, const float* __restrict__ k,
                  const float* __restrict__ v,
                  unsigned short* __restrict__ qx, unsigned short* __restrict__ kx,
                  unsigned short* __restrict__ vx) {
    const int y = blockIdx.y;
    const float* src = y == 0 ? q : (y == 1 ? k : v);
    unsigned short* dst = y == 0 ? qx : (y == 1 ? kx : vx);
    #pragma unroll
    for (int i = 0; i < 4; ++i) {
        int e = blockIdx.x * 4096 + i * 1024 + threadIdx.x * 4;
        float4 f = *reinterpret_cast<const float4*>(src + e);
        *reinterpret_cast<ushort4*>(dst + e) =
            make_ushort4(f2b(f.x), f2b(f.y), f2b(f.z), f2b(f.w));
    }
}

// ---------------------------------------------------------------------------
// Projection NT-GEMM (pure bf16): C[m][he] = sum_d X[m][d]*Wt[he][d].
// 8192x512x512, which: 0=Q 1=K 2=V. 128x64 tile, BK=64. (unchanged control)
// ---------------------------------------------------------------------------
__global__ __launch_bounds__(256, 3)
void proj_gemm(const unsigned short* __restrict__ qx,
               const unsigned short* __restrict__ kx,
               const unsigned short* __restrict__ vx,
               const unsigned short* __restrict__ wqt,
               const unsigned short* __restrict__ wkt,
               const unsigned short* __restrict__ wvt,
               unsigned short* __restrict__ qb, unsigned short* __restrict__ kb,
               unsigned short* __restrict__ vtb) {
    const int m0  = blockIdx.x * 128;
    const int no0 = blockIdx.y * 64;
    const int which = blockIdx.z;
    const int tid = threadIdx.x;
    const int wave = tid >> 6, lane = tid & 63;
    const int quad = lane >> 4, l16 = lane & 15;

    const unsigned short* X = which == 0 ? qx : (which == 1 ? kx : vx);
    const unsigned short* W = which == 0 ? wqt : (which == 1 ? wkt : wvt);

    __shared__ unsigned short Ab[2][8192];   // 2 x 16 KB (128 rows x 128 B)
    __shared__ unsigned short Bb[2][4096];   // 2 x  8 KB ( 64 rows x 128 B)

    const unsigned short* Xp = X + (size_t)m0 * D_;
    const unsigned short* Wp = W + (size_t)no0 * D_;

    const int swzF = (l16 & 7) << 4;          // frag-read byte XOR (row≡l16 mod 8)
    const int r8   = lane >> 3;               // stage: row within 8-row slab
    const int sg   = lane & 7;                // stage: 16B slot in 128B row
    const int colK = (sg * 16) ^ ((r8 & 7) << 4);  // pre-swizzled source byte col

    #define PROJ_STAGE(kt, buf)                                                \
        {   _Pragma("unroll")                                                  \
            for (int i = 0; i < 4; ++i)                                        \
                async_copy16(                                                  \
                    (const char*)(Xp + (size_t)(wave * 32 + i * 8 + r8) * D_ + \
                                  (kt) * 64) + colK,                           \
                    &Ab[buf][(wave * 32 + i * 8) * 64]);                       \
            _Pragma("unroll")                                                  \
            for (int i = 0; i < 2; ++i)                                        \
                async_copy16(                                                  \
                    (const char*)(Wp + (size_t)(wave * 16 + i * 8 + r8) * D_ + \
                                  (kt) * 64) + colK,                           \
                    &Bb[buf][(wave * 16 + i * 8) * 64]);                       \
        }

    PROJ_STAGE(0, 0)
    __syncthreads();                          // vmcnt drain: tile 0 resident

    const f32x4 z = {0.f, 0.f, 0.f, 0.f};
    f32x4 acc[2][4];
    #pragma unroll
    for (int i = 0; i < 2; ++i)
        #pragma unroll
        for (int j = 0; j < 4; ++j) acc[i][j] = z;

    for (int kt = 0; kt < 8; ++kt) {
        const int cur = kt & 1;
        if (kt + 1 < 8) PROJ_STAGE(kt + 1, 1 - cur)   // in flight over compute
        #pragma unroll
        for (int kk = 0; kk < 2; ++kk) {
            const int co = ((kk * 64 + quad * 16) ^ swzF) >> 1;
            bf16x8 bfr[4];
            #pragma unroll
            for (int nt = 0; nt < 4; ++nt)
                bfr[nt] = ld_frag(&Bb[cur][(nt * 16 + l16) * 64 + co]);
            #pragma unroll
            for (int mt = 0; mt < 2; ++mt) {
                bf16x8 af = ld_frag(&Ab[cur][(wave * 32 + mt * 16 + l16) * 64 + co]);
                #pragma unroll
                for (int nt = 0; nt < 4; ++nt)
                    acc[mt][nt] = __builtin_amdgcn_mfma_f32_16x16x32_bf16(
                        af, bfr[nt], acc[mt][nt], 0, 0, 0);
            }
        }
        __syncthreads();                      // drains vmcnt (tile kt+1) + lgkm
    }

    // epilogue: overlay staging on Ab (32 KB contiguous)
    if (which != 2) {
        unsigned short (*Os)[72] = reinterpret_cast<unsigned short(*)[72]>(&Ab[0][0]);
        #pragma unroll
        for (int mt = 0; mt < 2; ++mt)
            #pragma unroll
            for (int nt = 0; nt < 4; ++nt)
                #pragma unroll
                for (int r = 0; r < 4; ++r)
                    Os[wave * 32 + mt * 16 + quad * 4 + r][nt * 16 + l16] =
                        f2b(acc[mt][nt][r]);
        __syncthreads();
        unsigned short* Y = (which == 0 ? qb : kb);
        #pragma unroll
        for (int i = 0; i < 4; ++i) {           // 128 rows x 8 uint4
            int idx = tid + i * 256;
            int row = idx >> 3, seg = idx & 7;
            *reinterpret_cast<uint4*>(Y + (size_t)(m0 + row) * D_ + no0 + seg * 8) =
                *reinterpret_cast<const uint4*>(&Os[row][seg * 8]);
        }
    } else {
        unsigned short (*Ot)[136] = reinterpret_cast<unsigned short(*)[136]>(&Ab[0][0]);
        #pragma unroll
        for (int mt = 0; mt < 2; ++mt)
            #pragma unroll
            for (int nt = 0; nt < 4; ++nt) {
                ushort4 o = make_ushort4(f2b(acc[mt][nt][0]), f2b(acc[mt][nt][1]),
                                         f2b(acc[mt][nt][2]), f2b(acc[mt][nt][3]));
                *reinterpret_cast<ushort4*>(
                    &Ot[nt * 16 + l16][wave * 32 + mt * 16 + quad * 4]) = o;
            }
        __syncthreads();
        const int b = m0 >> 11, nloc = m0 & 2047;
        #pragma unroll
        for (int i = 0; i < 4; ++i) {           // 64 he-rows x 16 uint4
            int idx = tid + i * 256;
            int lhe = idx >> 4, seg = idx & 15;
            int ghe = no0 + lhe;                 // h = ghe>>6, e = ghe&63
            *reinterpret_cast<uint4*>(
                vtb + ((size_t)(b * H_ + (ghe >> 6)) * E_ + (ghe & 63)) * NSEQ +
                nloc + seg * 8) =
                *reinterpret_cast<const uint4*>(&Ot[lhe][seg * 8]);
        }
    }
    #undef PROJ_STAGE
}

// ---------------------------------------------------------------------------
// Flash attention, 32x32x16 MFMA, in-register P (T12 permlane exchange).
// 64-row Q tiles (grid 1024), 256 threads = 4 waves tiling S 2x2:
//   wk = wave>>1 (key half), wq = wave&1 (q half).
//   S-block = mfma(K-frag, Q-frag): C[key = (reg&3)+8*(reg>>2)+4*hi][q = lane&31]
//   P = exp(S) stays in registers; v_permlane32_swap_b32 converts the C-layout
//   to the PV B-operand layout (lane&31 = q col, k = hi*8+j) — NO P LDS.
//   O-partial[64e][32q] per wave over its 32 keys; wk pairs combined once in
//   the epilogue through LDS. m=0 softmax, deferred l.
// Per-wave-iter DS: 4 K + 4 V b128 reads (was 18 b128 + 4 b64 in r3).
// LDS = Ks+Vs dbuf = 32 KB -> 4 blocks/CU, 16 waves/CU, grid 1024 no tail.
// ---------------------------------------------------------------------------
__global__ __launch_bounds__(256, 3)
void attn_kernel(const unsigned short* __restrict__ qbp,
                 const unsigned short* __restrict__ kbp,
                 const unsigned short* __restrict__ vtbp,
                 unsigned short* __restrict__ aob) {
    const int L = blockIdx.x;
    const int bh = L & 31, qt = L >> 5;      // L%8 pattern -> XCD K/V affinity
    const int b = bh >> 3, h = bh & 7;
    const int n0 = qt * 64;
    const int tid = threadIdx.x;
    const int wave = tid >> 6, lane = tid & 63;
    const int wk = wave >> 1, wq = wave & 1;
    const int l32 = lane & 31, hi = lane >> 5;

    __shared__ unsigned short Ks[2][4096];   // 16 KiB (dbuf K, 64x64, 128-B rows)
    __shared__ unsigned short Vs[2][4096];   // 16 KiB (dbuf V^T)

    const unsigned short* kbase = kbp + (size_t)(b * NSEQ) * D_ + h * 64;
    const unsigned short* vbase = vtbp + (size_t)(b * H_ + h) * E_ * NSEQ;

    const int r8   = lane >> 3;        // staging: row within an 8-row slab
    const int sg   = lane & 7;         //          16B slot within the 128B row
    const int colK = (sg * 16) ^ ((r8 & 7) << 4);  // pre-swizzled source column
    const int swz  = (lane & 7) << 4;  // frag-read byte XOR (row = l32 ≡ lane mod 8)

    // Q B-frags (32x32x16 B layout: lane&31 = q col, k-octet = hi):
    // qf[ks] = Q[n0 + wq*32 + l32][ks*16 + hi*8 .. +8]
    bf16x8 qf[4];
    #pragma unroll
    for (int ks = 0; ks < 4; ++ks)
        qf[ks] = ld_frag(qbp + (size_t)(b * NSEQ + n0 + wq * 32 + l32) * D_ +
                         h * 64 + ks * 16 + hi * 8);

    #define ATTN_STAGE(j, buf)                                                 \
        {   _Pragma("unroll")                                                  \
            for (int i = 0; i < 2; ++i) {                                      \
                async_copy16(                                                  \
                    (const char*)(kbase +                                      \
                        (size_t)((j) * 64 + wave * 16 + i * 8 + r8) * D_) + colK, \
                    &Ks[buf][wave * 1024 + i * 512]);                          \
                async_copy16(                                                  \
                    (const char*)(vbase +                                      \
                        (size_t)(wave * 16 + i * 8 + r8) * NSEQ + (j) * 64) + colK, \
                    &Vs[buf][wave * 1024 + i * 512]);                          \
            } }

    ATTN_STAGE(0, 0)
    __syncthreads();                            // vmcnt drain: tile 0 resident

    f32x16 oacc[2] = {};                        // O^T[eb*32 + crow][q], own keys
    float lacc = 0.f;

    for (int j = 0; j < NSEQ / 64; ++j) {
        const int cur = j & 1;
        if (j + 1 < NSEQ / 64) ATTN_STAGE(j + 1, 1 - cur)   // in flight over compute

        const unsigned short* Kc = Ks[cur];
        const unsigned short* Vc = Vs[cur];

        // S-block = mfma(K, Q): A = K[key = wk*32 + l32][d-octet hi]
        f32x16 sacc = {};
        #pragma unroll
        for (int ks = 0; ks < 4; ++ks) {
            bf16x8 kf = ld_frag(
                &Kc[(wk * 32 + l32) * 64 + ((((ks * 32 + hi * 16)) ^ swz) >> 1)]);
            sacc = __builtin_amdgcn_mfma_f32_32x32x16_bf16(kf, qf[ks], sacc, 0, 0, 0);
        }

        // exp (m=0); lane holds P for 16 keys: k_local = (r&3)+8*(r>>2)+4*hi
        float p[16];
        #pragma unroll
        for (int r = 0; r < 16; ++r) p[r] = __expf(sacc[r]);
        lacc += ((p[0] + p[1]) + (p[2] + p[3])) + ((p[4] + p[5]) + (p[6] + p[7])) +
                (((p[8] + p[9]) + (p[10] + p[11])) + ((p[12] + p[13]) + (p[14] + p[15])));

        // Build PV B-frags in-register: pack bf16 pairs, then swap lane-halves.
        // Slice s covers k_local s*16..s*16+15; B word w needs k = hi*8 + 2w,2w+1.
        #pragma unroll
        for (int s = 0; s < 2; ++s) {
            unsigned x0 = pk2(p[s * 8 + 0], p[s * 8 + 1]);
            unsigned x1 = pk2(p[s * 8 + 2], p[s * 8 + 3]);
            unsigned y0 = pk2(p[s * 8 + 4], p[s * 8 + 5]);
            unsigned y1 = pk2(p[s * 8 + 6], p[s * 8 + 7]);
            // after swap: x' = [x_lo | y_lo] (word0), y' = [x_hi | y_hi] (word2)
            asm volatile("v_permlane32_swap_b32 %0, %1" : "+v"(x0), "+v"(y0));
            asm volatile("v_permlane32_swap_b32 %0, %1" : "+v"(x1), "+v"(y1));
            uint4 u = make_uint4(x0, x1, y0, y1);
            bf16x8 pb = __builtin_bit_cast(bf16x8, u);
            // O^T += V^T·P : A = V^T[e = eb*32 + l32][keys wk*32 + s*16 + hi*8..]
            #pragma unroll
            for (int eb = 0; eb < 2; ++eb) {
                bf16x8 vf = ld_frag(
                    &Vc[(eb * 32 + l32) * 64 +
                        ((((wk * 64 + s * 32 + hi * 16)) ^ swz) >> 1)]);
                oacc[eb] = __builtin_amdgcn_mfma_f32_32x32x16_bf16(
                    vf, pb, oacc[eb], 0, 0, 0);
            }
        }

        __syncthreads();   // drains vmcnt (tile j+1 committed) + lgkm; flips buffers
    }

    // ---- epilogue: combine wk pairs through LDS (Ks/Vs dead), normalize ----
    lacc += __shfl_xor(lacc, 32);              // wave partial l(q), q = l32
    float* Of = reinterpret_cast<float*>(&Ks[0][0]);   // [wq][32 q][64 e] = 16 KB
    float* Lf = reinterpret_cast<float*>(&Vs[0][0]);   // [wq][32 q]
    if (wk == 0) {
        #pragma unroll
        for (int eb = 0; eb < 2; ++eb)
            #pragma unroll
            for (int rg = 0; rg < 4; ++rg) {
                f32x4 v = {oacc[eb][rg * 4 + 0], oacc[eb][rg * 4 + 1],
                           oacc[eb][rg * 4 + 2], oacc[eb][rg * 4 + 3]};
                *reinterpret_cast<f32x4*>(
                    &Of[(wq * 32 + l32) * 64 + eb * 32 + rg * 8 + hi * 4]) = v;
            }
        if (hi == 0) Lf[wq * 32 + l32] = lacc;
    }
    __syncthreads();
    if (wk == 1) {
        const float li = 1.0f / (lacc + Lf[wq * 32 + l32]);
        unsigned short* op =
            aob + (size_t)(b * NSEQ + n0 + wq * 32 + l32) * D_ + h * 64;
        #pragma unroll
        for (int eb = 0; eb < 2; ++eb)
            #pragma unroll
            for (int rg = 0; rg < 4; ++rg) {
                const f32x4 o = *reinterpret_cast<const f32x4*>(
                    &Of[(wq * 32 + l32) * 64 + eb * 32 + rg * 8 + hi * 4]);
                ushort4 st = make_ushort4(f2b((oacc[eb][rg * 4 + 0] + o.x) * li),
                                          f2b((oacc[eb][rg * 4 + 1] + o.y) * li),
                                          f2b((oacc[eb][rg * 4 + 2] + o.z) * li),
                                          f2b((oacc[eb][rg * 4 + 3] + o.w) * li));
                *reinterpret_cast<ushort4*>(op + eb * 32 + rg * 8 + hi * 4) = st;
            }
    }
    #undef ATTN_STAGE
}

// ---------------------------------------------------------------------------
// Output NT-GEMM: Out[m][o] = sum_d aob[m][d] * Wout[o][d]. 8192x512x512.
// Same global_load_lds structure as proj_gemm; fp32 direct-store epilogue.
// (unchanged control)
// ---------------------------------------------------------------------------
__global__ __launch_bounds__(256, 3)
void out_gemm(const unsigned short* __restrict__ A,
              const unsigned short* __restrict__ Wo,
              float* __restrict__ Out) {
    const int m0  = blockIdx.x * 128;
    const int no0 = blockIdx.y * 64;
    const int tid = threadIdx.x;
    const int wave = tid >> 6, lane = tid & 63;
    const int quad = lane >> 4, l16 = lane & 15;

    __shared__ unsigned short Ab[2][8192];
    __shared__ unsigned short Bb[2][4096];

    const unsigned short* Ap = A + (size_t)m0 * D_;
    const unsigned short* Bp = Wo + (size_t)no0 * D_;

    const int swzF = (l16 & 7) << 4;
    const int r8   = lane >> 3;
    const int sg   = lane & 7;
    const int colK = (sg * 16) ^ ((r8 & 7) << 4);

    #define OUT_STAGE(kt, buf)                                                 \
        {   _Pragma("unroll")                                                  \
            for (int i = 0; i < 4; ++i)                                        \
                async_copy16(                                                  \
                    (const char*)(Ap + (size_t)(wave * 32 + i * 8 + r8) * D_ + \
                                  (kt) * 64) + colK,                           \
                    &Ab[buf][(wave * 32 + i * 8) * 64]);                       \
            _Pragma("unroll")                                                  \
            for (int i = 0; i < 2; ++i)                                        \
                async_copy16(                                                  \
                    (const char*)(Bp + (size_t)(wave * 16 + i * 8 + r8) * D_ + \
                                  (kt) * 64) + colK,                           \
                    &Bb[buf][(wave * 16 + i * 8) * 64]);                       \
        }

    OUT_STAGE(0, 0)
    __syncthreads();

    const f32x4 z = {0.f, 0.f, 0.f, 0.f};
    f32x4 acc[2][4];
    #pragma unroll
    for (int i = 0; i < 2; ++i)
        #pragma unroll
        for (int j = 0; j < 4; ++j) acc[i][j] = z;

    for (int kt = 0; kt < 8; ++kt) {
        const int cur = kt & 1;
        if (kt + 1 < 8) OUT_STAGE(kt + 1, 1 - cur)
        #pragma unroll
        for (int kk = 0; kk < 2; ++kk) {
            const int co = ((kk * 64 + quad * 16) ^ swzF) >> 1;
            bf16x8 bfr[4];
            #pragma unroll
            for (int nt = 0; nt < 4; ++nt)
                bfr[nt] = ld_frag(&Bb[cur][(nt * 16 + l16) * 64 + co]);
            #pragma unroll
            for (int mt = 0; mt < 2; ++mt) {
                bf16x8 af = ld_frag(&Ab[cur][(wave * 32 + mt * 16 + l16) * 64 + co]);
                #pragma unroll
                for (int nt = 0; nt < 4; ++nt)
                    acc[mt][nt] = __builtin_amdgcn_mfma_f32_16x16x32_bf16(
                        af, bfr[nt], acc[mt][nt], 0, 0, 0);
            }
        }
        __syncthreads();
    }
    #pragma unroll
    for (int mt = 0; mt < 2; ++mt)
        #pragma unroll
        for (int nt = 0; nt < 4; ++nt)
            #pragma unroll
            for (int r = 0; r < 4; ++r)
                Out[(size_t)(m0 + wave * 32 + mt * 16 + quad * 4 + r) * D_ +
                    no0 + nt * 16 + l16] = acc[mt][nt][r];
    #undef OUT_STAGE
}

// ---------------------------------------------------------------------------
extern "C" void kernel_launch(void* const* d_in, const int* in_sizes, int n_in,
                              void* d_out, int out_size, void* d_ws, size_t ws_size,
                              hipStream_t stream) {
    const float* keys   = (const float*)d_in[0];
    const float* values = (const float*)d_in[1];
    const float* query  = (const float*)d_in[2];
    const float* Wk     = (const float*)d_in[3];
    const float* Wv     = (const float*)d_in[4];
    const float* Wq     = (const float*)d_in[5];
    const float* Wout   = (const float*)d_in[6];
    float* out = (float*)d_out;

    unsigned short* ws16 = (unsigned short*)d_ws;
    const size_t XN = (size_t)B_ * NSEQ * D_;      // 4,194,304
    const size_t WN = (size_t)H_ * D_ * E_;        // 262,144
    unsigned short* wkt = ws16;                    // [he][d]
    unsigned short* wvt = wkt + WN;
    unsigned short* wqt = wvt + WN;                // pre-scaled by 1/64
    unsigned short* wob = wqt + WN;
    unsigned short* qb  = wob + WN;                // [8192][512], col=h*64+e
    unsigned short* kb  = qb + XN;                 // [8192][512]
    unsigned short* vtb = kb + XN;                 // [b][h][e][n]
    unsigned short* aob = vtb + XN;                // [8192][512] head-concat
    unsigned short* qx  = aob + XN;                // bf16 query  [8192][512]
    unsigned short* kx  = qx + XN;                 // bf16 keys   [8192][512]
    unsigned short* vx  = aob;                     // bf16 values ALIASES aob:
                                                   // vx dead after proj; aob
                                                   // written only by attn (later)

    cast_w_kernel<<<dim3(1024, 4), 256, 0, stream>>>(Wk, Wv, Wq, Wout,
                                                     wkt, wvt, wqt, wob);

    xcast_kernel<<<dim3(1024, 3), 256, 0, stream>>>(query, keys, values,
                                                    qx, kx, vx);

    proj_gemm<<<dim3(64, 8, 3), 256, 0, stream>>>(
        qx, kx, vx, wqt, wkt, wvt, qb, kb, vtb);

    attn_kernel<<<dim3(1024), 256, 0, stream>>>(qb, kb, vtb, aob);

    out_gemm<<<dim3(64, 8), 256, 0, stream>>>(aob, wob, out);
}